// Round 10
// baseline (9377.318 us; speedup 1.0000x reference)
//
#include <hip/hip_runtime.h>
#include <hip/hip_bf16.h>
#include <math.h>

typedef __hip_bfloat16 bf16;

#define NB 4
#define NS 4096
#define NE 512
#define NH 8
#define NL 4
#define NA 3
#define ND 64
#define NC 64
#define NW 64
#define NF 2048
#define NVOC 17
#define NTOK (NB * NS)   // 16384

__device__ __forceinline__ float b2f(bf16 v) { return __bfloat162float(v); }
__device__ __forceinline__ float u2f(unsigned short u) { return __uint_as_float((unsigned)u << 16); }
__device__ __forceinline__ float ldw(const void* p, size_t i, int f32) {
  return f32 ? ((const float*)p)[i] : b2f(((const bf16*)p)[i]);
}

// ---------------- dtype detect (tok_emb row 0 all-zero <=> fp32 spans words 0..511) ----------------
__global__ void detect_kernel(const void* __restrict__ tok, int* __restrict__ dflag) {
  if (threadIdx.x == 0 && blockIdx.x == 0) {
    const unsigned* w = (const unsigned*)tok;
    int any = 0;
    for (int i = 256; i < 512; i++) any |= (w[i] != 0u);
    dflag[0] = any ? 0 : 1;   // 1 = fp32 inputs, 0 = bf16 inputs
  }
}

// ---------------- diagnostic fill (ws_size too small) ----------------
__global__ __launch_bounds__(256) void fill_out_kernel(float* __restrict__ out, int n, float val) {
  int i = blockIdx.x * 256 + threadIdx.x;
  if (i < n) out[i] = val;
}

// ---------------- zero fill ----------------
__global__ __launch_bounds__(256) void zero_kernel(float* __restrict__ p, int n) {
  int i = blockIdx.x * 256 + threadIdx.x;
  if (i < n) p[i] = 0.f;
}

// ---------------- embeddings + shift-right ----------------
__global__ __launch_bounds__(256) void embed_kernel(
    const int* __restrict__ value, const int* __restrict__ depth, const int* __restrict__ pos,
    const void* __restrict__ sos, const void* __restrict__ tok_emb,
    const void* __restrict__ depth_emb, const void* __restrict__ pos_emb,
    float* __restrict__ x, const int* __restrict__ dflag) {
  int f32 = dflag[0];
  int i = blockIdx.x * 256 + threadIdx.x;
  if (i >= NTOK * NE) return;
  int e = i & (NE - 1);
  int bs = i >> 9;
  int s = bs & (NS - 1);
  int b = bs >> 12;
  float v;
  if (s == 0) {
    v = ldw(sos, e, f32);
  } else {
    int src = b * NS + (s - 1);
    float acc = ldw(tok_emb, (size_t)value[src] * NE + e, f32)
              + ldw(depth_emb, (size_t)depth[src] * NE + e, f32);
#pragma unroll
    for (int a = 0; a < NA; a++)
      acc += ldw(pos_emb, ((size_t)a * 65 + pos[src * NA + a]) * NE + e, f32);
    v = acc;
  }
  x[i] = v;
}

// ---------------- layer norm, one wave per row ----------------
__global__ __launch_bounds__(256) void ln_kernel(
    const float* __restrict__ x, const void* __restrict__ gam, const void* __restrict__ bet,
    size_t off, float* __restrict__ out, const int* __restrict__ dflag) {
  int f32 = dflag[0];
  int row = blockIdx.x * 4 + (threadIdx.x >> 6);
  int lane = threadIdx.x & 63;
  const float* xr = x + (size_t)row * NE;
  float v[8];
#pragma unroll
  for (int i = 0; i < 8; i++) v[i] = xr[lane + i * 64];
  float s = 0.f;
#pragma unroll
  for (int i = 0; i < 8; i++) s += v[i];
#pragma unroll
  for (int o = 32; o; o >>= 1) s += __shfl_xor(s, o);
  float m = s * (1.0f / NE);
  float sq = 0.f;
#pragma unroll
  for (int i = 0; i < 8; i++) { float d = v[i] - m; sq += d * d; }
#pragma unroll
  for (int o = 32; o; o >>= 1) sq += __shfl_xor(sq, o);
  float rs = 1.0f / sqrtf(sq * (1.0f / NE) + 1e-5f);
  float* orow = out + (size_t)row * NE;
#pragma unroll
  for (int i = 0; i < 8; i++) {
    int e = lane + i * 64;
    orow[e] = (v[i] - m) * rs * ldw(gam, off + e, f32) + ldw(bet, off + e, f32);
  }
}

// ---------------- GEMM core: 128x128 tile, BK=32, 8x8 microtile, conflict-free LDS ----------------
// Per-thread K accumulation is sequential k=0..K-1 (bit-stable across tilings).
template <int ACT>
__device__ __forceinline__ void gemm_body(
    const float* __restrict__ A, const void* __restrict__ Bw, size_t bwoff, int ldb,
    const void* bias, size_t biasoff, const float* resid, float* C,
    int N, int K, int f32, int bm, int bn) {
  __shared__ float As[32][132];   // [k][m]  16.9 KB
  __shared__ float Bs[32][132];   // [k][n]  16.9 KB
  int tid = threadIdx.x;
  int ty = tid >> 4, tx = tid & 15;
  float acc[8][8];
#pragma unroll
  for (int i = 0; i < 8; i++)
#pragma unroll
    for (int j = 0; j < 8; j++) acc[i][j] = 0.f;
  int arow = tid >> 1;              // 0..127
  int acol = (tid & 1) << 4;        // 0 | 16
  int brow = tid >> 3;              // 0..31
  int bcol = (tid & 7) << 4;        // 0..112

  const float* Aptr = A + (size_t)(bm + arow) * K + acol;
  float4 pa[4];
  float4 pb[4];
  uint4 pbu[2];
#pragma unroll
  for (int j = 0; j < 4; j++) pa[j] = *(const float4*)(Aptr + 4 * j);
  {
    size_t boff = bwoff + (size_t)brow * ldb + bn + bcol;
    if (f32) {
#pragma unroll
      for (int j = 0; j < 4; j++) pb[j] = *(const float4*)((const float*)Bw + boff + 4 * j);
    } else {
      pbu[0] = *(const uint4*)((const bf16*)Bw + boff);
      pbu[1] = *(const uint4*)((const bf16*)Bw + boff + 8);
    }
  }

  for (int k0 = 0; k0 < K; k0 += 32) {
#pragma unroll
    for (int j = 0; j < 4; j++) {
      As[acol + 4 * j + 0][arow] = pa[j].x;
      As[acol + 4 * j + 1][arow] = pa[j].y;
      As[acol + 4 * j + 2][arow] = pa[j].z;
      As[acol + 4 * j + 3][arow] = pa[j].w;
    }
    if (f32) {
#pragma unroll
      for (int j = 0; j < 4; j++) {
        Bs[brow][bcol + 4 * j + 0] = pb[j].x;
        Bs[brow][bcol + 4 * j + 1] = pb[j].y;
        Bs[brow][bcol + 4 * j + 2] = pb[j].z;
        Bs[brow][bcol + 4 * j + 3] = pb[j].w;
      }
    } else {
      union { uint4 u; unsigned short s[8]; } r0, r1;
      r0.u = pbu[0]; r1.u = pbu[1];
#pragma unroll
      for (int j = 0; j < 8; j++) Bs[brow][bcol + j] = u2f(r0.s[j]);
#pragma unroll
      for (int j = 0; j < 8; j++) Bs[brow][bcol + 8 + j] = u2f(r1.s[j]);
    }
    __syncthreads();
    if (k0 + 32 < K) {
#pragma unroll
      for (int j = 0; j < 4; j++) pa[j] = *(const float4*)(Aptr + k0 + 32 + 4 * j);
      size_t boff = bwoff + (size_t)(k0 + 32 + brow) * ldb + bn + bcol;
      if (f32) {
#pragma unroll
        for (int j = 0; j < 4; j++) pb[j] = *(const float4*)((const float*)Bw + boff + 4 * j);
      } else {
        pbu[0] = *(const uint4*)((const bf16*)Bw + boff);
        pbu[1] = *(const uint4*)((const bf16*)Bw + boff + 8);
      }
    }
#pragma unroll
    for (int kk = 0; kk < 32; kk++) {
      float4 aA = *(const float4*)&As[kk][ty << 3];
      float4 aB = *(const float4*)&As[kk][(ty << 3) + 4];
      float4 bA = *(const float4*)&Bs[kk][tx << 2];          // cols tx*4..+3
      float4 bB = *(const float4*)&Bs[kk][64 + (tx << 2)];   // cols 64+tx*4..+3
      float av[8] = {aA.x, aA.y, aA.z, aA.w, aB.x, aB.y, aB.z, aB.w};
      float bv[8] = {bA.x, bA.y, bA.z, bA.w, bB.x, bB.y, bB.z, bB.w};
#pragma unroll
      for (int i = 0; i < 8; i++)
#pragma unroll
        for (int j = 0; j < 8; j++)
          acc[i][j] += av[i] * bv[j];
    }
    __syncthreads();
  }
#pragma unroll
  for (int i = 0; i < 8; i++) {
    int row = bm + (ty << 3) + i;
    int c0 = bn + (tx << 2);
    int c1 = bn + 64 + (tx << 2);
    float o0[4], o1[4];
#pragma unroll
    for (int j = 0; j < 4; j++) { o0[j] = acc[i][j]; o1[j] = acc[i][j + 4]; }
    if (bias) {
#pragma unroll
      for (int j = 0; j < 4; j++) {
        o0[j] += ldw(bias, biasoff + c0 + j, f32);
        o1[j] += ldw(bias, biasoff + c1 + j, f32);
      }
    }
    if (ACT == 1) {
#pragma unroll
      for (int j = 0; j < 4; j++) {
        float t0 = 0.7978845608028654f * (o0[j] + 0.044715f * o0[j] * o0[j] * o0[j]);
        o0[j] = 0.5f * o0[j] * (1.0f + tanhf(t0));
        float t1 = 0.7978845608028654f * (o1[j] + 0.044715f * o1[j] * o1[j] * o1[j]);
        o1[j] = 0.5f * o1[j] * (1.0f + tanhf(t1));
      }
    }
    size_t p0 = (size_t)row * N + c0;
    size_t p1 = (size_t)row * N + c1;
    if (resid) {
      float4 r0 = *(const float4*)(resid + p0);
      float4 r1 = *(const float4*)(resid + p1);
      o0[0] += r0.x; o0[1] += r0.y; o0[2] += r0.z; o0[3] += r0.w;
      o1[0] += r1.x; o1[1] += r1.y; o1[2] += r1.z; o1[3] += r1.w;
    }
    *(float4*)(C + p0) = make_float4(o0[0], o0[1], o0[2], o0[3]);
    *(float4*)(C + p1) = make_float4(o1[0], o1[1], o1[2], o1[3]);
  }
}

template <int ACT>
__global__ __launch_bounds__(256) void gemm_kernel(
    const float* __restrict__ A, const void* __restrict__ Bw, size_t bwoff, int ldb,
    const void* bias, size_t biasoff, const float* resid, float* C,
    int N, int K, const int* __restrict__ dflag) {
  gemm_body<ACT>(A, Bw, bwoff, ldb, bias, biasoff, resid, C, N, K,
                 dflag[0], blockIdx.y << 7, blockIdx.x << 7);
}

// fused Q/K/V: blockIdx.x in [0,12): sel = x>>2 picks weight/output, (x&3) is column block
__global__ __launch_bounds__(256) void gemm_qkv_kernel(
    const float* __restrict__ A,
    const void* __restrict__ Wq, const void* __restrict__ Wk, const void* __restrict__ Wv,
    size_t bwoff, float* __restrict__ Cq, float* __restrict__ Ck, float* __restrict__ Cv,
    const int* __restrict__ dflag) {
  int sel = blockIdx.x >> 2;
  const void* Bw = (sel == 0) ? Wq : ((sel == 1) ? Wk : Wv);
  float* C = (sel == 0) ? Cq : ((sel == 1) ? Ck : Cv);
  gemm_body<0>(A, Bw, bwoff, NE, nullptr, 0, nullptr, C, NE, NE,
               dflag[0], blockIdx.y << 7, (blockIdx.x & 3) << 7);
}

// ---------------- normalized means in fp64 ----------------
__global__ __launch_bounds__(64) void mnd_kernel(const void* __restrict__ means,
                                                 double* __restrict__ mnd,
                                                 const int* __restrict__ dflag) {
  __shared__ double s[64];
  int f32 = dflag[0];
  int vblk = blockIdx.x;          // (l*NH + h)*NC + c
  int d = threadIdx.x;
  double m = (double)ldw(means, (size_t)vblk * ND + d, f32);
  s[d] = m * m;
  __syncthreads();
  for (int st = 32; st; st >>= 1) { if (d < st) s[d] += s[d + st]; __syncthreads(); }
  mnd[(size_t)vblk * ND + d] = m / (sqrt(s[0]) + 1e-8);
}

// ---------------- per-(token,head) 1/(||q||+1e-8) ----------------
__global__ __launch_bounds__(64) void rq_kernel(const float* __restrict__ q, double* __restrict__ rqd) {
  int bid = blockIdx.x;           // token*NH + head
  int tok = bid >> 3, h = bid & 7;
  int d = threadIdx.x;
  double v = (double)q[(size_t)tok * NE + h * ND + d];
  double ss = v * v;
#pragma unroll
  for (int o = 32; o; o >>= 1) ss += __shfl_xor(ss, o);
  if (d == 0) rqd[bid] = 1.0 / (sqrt(ss) + 1e-8);
}

// ---------------- routing: fp64 dists + top-64, XCD-swizzled blocks ----------------
// blockIdx.x = c*32 + b*8 + h  -> all blocks of head h share an XCD (q slice 4MB = L2)
__global__ __launch_bounds__(256) void route_kernel(
    const float* __restrict__ q, const double* __restrict__ mnd,
    const double* __restrict__ rqd, int* __restrict__ idxout) {
  __shared__ unsigned long long keys[NS];   // 32 KB
  __shared__ unsigned long long wred[4];
  __shared__ double mc[ND];
  __shared__ int winner;
  int bid = blockIdx.x;
  int h = bid & 7;
  int b = (bid >> 3) & 3;
  int c = bid >> 5;
  int bhc = ((b * NH + h) * NC) + c;
  int t = threadIdx.x;
  if (t < ND) mc[t] = mnd[((size_t)h * NC + c) * ND + t];
  __syncthreads();
  for (int n = t; n < NS; n += 256) {
    const float4* qp = (const float4*)(q + (size_t)(b * NS + n) * NE + h * ND);
    double acc = 0.0;
#pragma unroll
    for (int j = 0; j < 16; j++) {
      float4 f = qp[j];
      acc += (double)f.x * mc[4 * j + 0];
      acc += (double)f.y * mc[4 * j + 1];
      acc += (double)f.z * mc[4 * j + 2];
      acc += (double)f.w * mc[4 * j + 3];
    }
    double dist = acc * rqd[(size_t)(b * NS + n) * NH + h];
    long long sb = __double_as_longlong(dist);
    unsigned long long u = (unsigned long long)sb;
    u = (sb < 0) ? ~u : (u | 0x8000000000000000ULL);
    keys[n] = (u & 0xFFFFFFFFFFFFF000ULL) | (unsigned long long)(NS - 1 - n);
  }
  __syncthreads();
  unsigned long long lm = 0;
  for (int n = t; n < NS; n += 256) { if (keys[n] > lm) lm = keys[n]; }
  for (int it = 0; it < NW; it++) {
    unsigned long long best = lm;
#pragma unroll
    for (int o = 32; o; o >>= 1) {
      unsigned long long ot = __shfl_down(best, o);
      if (ot > best) best = ot;
    }
    if ((t & 63) == 0) wred[t >> 6] = best;
    __syncthreads();
    if (t == 0) {
      best = wred[0];
      for (int w = 1; w < 4; w++) if (wred[w] > best) best = wred[w];
      int n = (NS - 1) - (int)(best & 0xFFFULL);
      idxout[(size_t)bhc * NW + it] = n;
      keys[n] = 0;
      winner = n;
    }
    __syncthreads();
    if ((winner & 255) == t) {
      lm = 0;
      for (int n = t; n < NS; n += 256) { if (keys[n] > lm) lm = keys[n]; }
    }
  }
}

// ---------------- per-(token,head) selection count ----------------
__global__ __launch_bounds__(256) void cnt_kernel(const int* __restrict__ idxb, float* __restrict__ cnt) {
  int i = blockIdx.x * 256 + threadIdx.x;   // NB*NH*NC*NW = 131072
  int bhc = i >> 6;
  int h = (bhc >> 6) & (NH - 1);
  int b = bhc >> 9;
  atomicAdd(&cnt[(size_t)(b * NS + idxb[i]) * NH + h], 1.0f);
}

// ---------------- bucket attention, all heads; scatter (attn/cnt) into obuf (pre-Wo) ----------------
__global__ __launch_bounds__(256) void attn_kernel(
    const float* __restrict__ q, const float* __restrict__ k, const float* __restrict__ v,
    const int* __restrict__ idxb, const int* __restrict__ value, const float* __restrict__ cnt,
    float* __restrict__ obuf) {
  __shared__ float qs[NW * (ND + 1)];
  __shared__ float ks[NW * (ND + 1)];
  __shared__ float sc[NW * (NW + 1)];
  __shared__ int idxs[NW];
  __shared__ float kmv[NW];
  __shared__ float cinv[NW];
  int bhc = blockIdx.x;                 // (b*NH + h)*NC + c
  int h = (bhc >> 6) & (NH - 1);
  int b = bhc >> 9;
  int t = threadIdx.x;
  if (t < NW) {
    int n = idxb[(size_t)bhc * NW + t];
    idxs[t] = n;
    kmv[t] = (value[b * NS + n] != 0) ? 1.f : 0.f;
    cinv[t] = 1.0f / fmaxf(cnt[(size_t)(b * NS + n) * NH + h], 1.0f);
  }
  __syncthreads();
  for (int p = t; p < NW * ND; p += 256) {
    int w = p >> 6, d = p & (ND - 1);
    size_t src = (size_t)(b * NS + idxs[w]) * NE + h * ND + d;
    qs[w * (ND + 1) + d] = q[src];
    ks[w * (ND + 1) + d] = k[src];
  }
  __syncthreads();
  for (int p = t; p < NW * NW; p += 256) {
    int w = p >> 6, x = p & (NW - 1);
    float dot = 0.f;
#pragma unroll 16
    for (int d = 0; d < ND; d++) dot += qs[w * (ND + 1) + d] * ks[x * (ND + 1) + d];
    bool allowed = (idxs[w] >= idxs[x]) && (kmv[x] != 0.f);
    sc[w * (NW + 1) + x] = allowed ? dot * 0.125f : -1e9f;
  }
  __syncthreads();
  if (t < NW) {
    float mx = -3.4e38f;
    for (int x = 0; x < NW; x++) mx = fmaxf(mx, sc[t * (NW + 1) + x]);
    float sum = 0.f;
    for (int x = 0; x < NW; x++) {
      float e = expf(sc[t * (NW + 1) + x] - mx);
      sc[t * (NW + 1) + x] = e;
      sum += e;
    }
    float inv = cinv[t] / sum;
    for (int x = 0; x < NW; x++) sc[t * (NW + 1) + x] *= inv;
  }
  for (int p = t; p < NW * ND; p += 256) {
    int w = p >> 6, d = p & (ND - 1);
    ks[w * (ND + 1) + d] = v[(size_t)(b * NS + idxs[w]) * NE + h * ND + d];
  }
  __syncthreads();
  for (int p = t; p < NW * ND; p += 256) {
    int w = p >> 6, d = p & (ND - 1);
    float o = 0.f;
#pragma unroll 16
    for (int x = 0; x < NW; x++) o += sc[w * (NW + 1) + x] * ks[x * (ND + 1) + d];
    qs[w * (ND + 1) + d] = o;
  }
  __syncthreads();
  for (int p = t; p < NW * ND; p += 256) {
    int w = p >> 6, d = p & (ND - 1);
    atomicAdd(&obuf[(size_t)(b * NS + idxs[w]) * NE + h * ND + d], qs[w * (ND + 1) + d]);
  }
}

// ---------------- head: out[b,s,v] = x . head_w[v]; dtype-aware output ----------------
__global__ __launch_bounds__(256) void head_kernel(
    const float* __restrict__ x, const void* __restrict__ hw, void* __restrict__ out,
    const int* __restrict__ dflag) {
  int f32 = dflag[0];
  int gw = (blockIdx.x * 256 + threadIdx.x) >> 6;
  int lane = threadIdx.x & 63;
  if (gw >= NTOK * NVOC) return;
  int row = gw / NVOC, vv = gw % NVOC;
  const float* xr = x + (size_t)row * NE;
  float acc = 0.f;
  for (int e = lane; e < NE; e += 64) acc += xr[e] * ldw(hw, (size_t)vv * NE + e, f32);
#pragma unroll
  for (int o = 32; o; o >>= 1) acc += __shfl_down(acc, o);
  if (lane == 0) {
    if (f32) ((float*)out)[(size_t)row * NVOC + vv] = acc;
    else ((bf16*)out)[(size_t)row * NVOC + vv] = __float2bfloat16(acc);
  }
}

extern "C" void kernel_launch(void* const* d_in, const int* in_sizes, int n_in,
                              void* d_out, int out_size, void* d_ws, size_t ws_size,
                              hipStream_t stream) {
  const int* value = (const int*)d_in[0];
  const int* depth = (const int*)d_in[1];
  const int* pos = (const int*)d_in[2];
  const void* sos = d_in[3];
  const void* tok_emb = d_in[4];
  const void* depth_emb = d_in[5];
  const void* pos_emb = d_in[6];
  const void* ln1_s = d_in[7];
  const void* ln1_b = d_in[8];
  const void* Wq = d_in[9];
  const void* Wk = d_in[10];
  const void* Wv = d_in[11];
  const void* Wo = d_in[12];
  const void* means = d_in[13];
  const void* ln2_s = d_in[14];
  const void* ln2_b = d_in[15];
  const void* W1 = d_in[16];
  const void* b1 = d_in[17];
  const void* W2 = d_in[18];
  const void* b2 = d_in[19];
  const void* head_w = d_in[20];
  (void)in_sizes; (void)n_in;

  const size_t NX = (size_t)NTOK * NE;                 // 8,388,608 floats (32 MiB)

  const size_t NEED = 170917896ULL;                    // ~163.0 MiB
  if (ws_size < NEED) {
    float val = (float)(unsigned)(ws_size >> 20) * 1000.0f;
    fill_out_kernel<<<(out_size + 255) / 256, 256, 0, stream>>>((float*)d_out, out_size, val);
    return;
  }

  float* xbuf = (float*)d_ws;
  float* hbuf = xbuf + NX;       // LN1 output, then pre-Wo attn accumulator
  float* qbuf = hbuf + NX;       // q all heads; later LN2 output
  float* kbuf = qbuf + NX;       // k; kbuf..vbuf doubles as FFN mid (64 MiB)
  float* vbuf = kbuf + NX;       // v
  double* mndbuf = (double*)(vbuf + NX);
  double* rqdbuf = mndbuf + (size_t)NL * NH * NC * ND;
  float* cntbuf = (float*)(rqdbuf + (size_t)NTOK * NH);
  int* idxbuf = (int*)(cntbuf + (size_t)NTOK * NH);
  int* dflag = idxbuf + (size_t)NB * NH * NC * NW;
  float* mid = kbuf;             // 8192 x 2048 fp32 = 64 MiB

  detect_kernel<<<1, 64, 0, stream>>>(tok_emb, dflag);
  mnd_kernel<<<NL * NH * NC, 64, 0, stream>>>(means, mndbuf, dflag);
  embed_kernel<<<(int)((NX + 255) / 256), 256, 0, stream>>>(
      value, depth, pos, sos, tok_emb, depth_emb, pos_emb, xbuf, dflag);

  const int CH = 8192;
  dim3 gqkv(12, NTOK / 128);                 // fused q,k,v: 1536 blocks
  dim3 g512(NE / 128, NTOK / 128);           // (4, 128)
  dim3 gW1(NF / 128, CH / 128);              // (16, 64)
  dim3 gW2(NE / 128, CH / 128);              // (4, 64)

  for (int l = 0; l < NL; l++) {
    size_t o_w = (size_t)l * NE * NE;
    size_t o_w1 = (size_t)l * NE * NF;
    size_t o_w2 = (size_t)l * NF * NE;
    size_t o_e = (size_t)l * NE;
    size_t o_f = (size_t)l * NF;

    ln_kernel<<<NTOK / 4, 256, 0, stream>>>(xbuf, ln1_s, ln1_b, o_e, hbuf, dflag);

    gemm_qkv_kernel<<<gqkv, 256, 0, stream>>>(hbuf, Wq, Wk, Wv, o_w, qbuf, kbuf, vbuf, dflag);

    rq_kernel<<<NTOK * NH, 64, 0, stream>>>(qbuf, rqdbuf);
    route_kernel<<<NB * NH * NC, 256, 0, stream>>>(
        qbuf, mndbuf + (size_t)l * NH * NC * ND, rqdbuf, idxbuf);
    zero_kernel<<<(NTOK * NH) / 256, 256, 0, stream>>>(cntbuf, NTOK * NH);
    cnt_kernel<<<(NB * NH * NC * NW) / 256, 256, 0, stream>>>(idxbuf, cntbuf);

    zero_kernel<<<(int)((NX + 255) / 256), 256, 0, stream>>>(hbuf, (int)NX);
    attn_kernel<<<NB * NH * NC, 256, 0, stream>>>(qbuf, kbuf, vbuf, idxbuf, value, cntbuf, hbuf);
    gemm_kernel<0><<<g512, 256, 0, stream>>>(hbuf, Wo, o_w, NE, nullptr, 0, xbuf,
                                             xbuf, NE, NE, dflag);

    ln_kernel<<<NTOK / 4, 256, 0, stream>>>(xbuf, ln2_s, ln2_b, o_e, qbuf, dflag);
    for (int ch = 0; ch < NTOK / CH; ch++) {
      const float* hch = qbuf + (size_t)ch * CH * NE;
      float* xch = xbuf + (size_t)ch * CH * NE;
      gemm_kernel<1><<<gW1, 256, 0, stream>>>(hch, W1, o_w1, NF, b1, o_f, nullptr,
                                              mid, NF, NE, dflag);
      gemm_kernel<0><<<gW2, 256, 0, stream>>>(mid, W2, o_w2, NE, b2, o_e, xch,
                                              xch, NE, NF, dflag);
    }
  }

  head_kernel<<<(NTOK * NVOC * 64 + 255) / 256, 256, 0, stream>>>(xbuf, head_w, d_out, dflag);
}

// Round 11
// 7847.620 us; speedup vs baseline: 1.1949x; 1.1949x over previous
//
#include <hip/hip_runtime.h>
#include <hip/hip_bf16.h>
#include <math.h>

typedef __hip_bfloat16 bf16;
typedef __attribute__((ext_vector_type(2))) float f2v;

#define NB 4
#define NS 4096
#define NE 512
#define NH 8
#define NL 4
#define NA 3
#define ND 64
#define NC 64
#define NW 64
#define NF 2048
#define NVOC 17
#define NTOK (NB * NS)   // 16384

__device__ __forceinline__ float b2f(bf16 v) { return __bfloat162float(v); }
__device__ __forceinline__ float u2f(unsigned short u) { return __uint_as_float((unsigned)u << 16); }
__device__ __forceinline__ float ldw(const void* p, size_t i, int f32) {
  return f32 ? ((const float*)p)[i] : b2f(((const bf16*)p)[i]);
}

// ---------------- dtype detect (tok_emb row 0 all-zero <=> fp32 spans words 0..511) ----------------
__global__ void detect_kernel(const void* __restrict__ tok, int* __restrict__ dflag) {
  if (threadIdx.x == 0 && blockIdx.x == 0) {
    const unsigned* w = (const unsigned*)tok;
    int any = 0;
    for (int i = 256; i < 512; i++) any |= (w[i] != 0u);
    dflag[0] = any ? 0 : 1;   // 1 = fp32 inputs, 0 = bf16 inputs
  }
}

// ---------------- diagnostic fill (ws_size too small) ----------------
__global__ __launch_bounds__(256) void fill_out_kernel(float* __restrict__ out, int n, float val) {
  int i = blockIdx.x * 256 + threadIdx.x;
  if (i < n) out[i] = val;
}

// ---------------- zero fill ----------------
__global__ __launch_bounds__(256) void zero_kernel(float* __restrict__ p, int n) {
  int i = blockIdx.x * 256 + threadIdx.x;
  if (i < n) p[i] = 0.f;
}

// ---------------- embeddings + shift-right ----------------
__global__ __launch_bounds__(256) void embed_kernel(
    const int* __restrict__ value, const int* __restrict__ depth, const int* __restrict__ pos,
    const void* __restrict__ sos, const void* __restrict__ tok_emb,
    const void* __restrict__ depth_emb, const void* __restrict__ pos_emb,
    float* __restrict__ x, const int* __restrict__ dflag) {
  int f32 = dflag[0];
  int i = blockIdx.x * 256 + threadIdx.x;
  if (i >= NTOK * NE) return;
  int e = i & (NE - 1);
  int bs = i >> 9;
  int s = bs & (NS - 1);
  int b = bs >> 12;
  float v;
  if (s == 0) {
    v = ldw(sos, e, f32);
  } else {
    int src = b * NS + (s - 1);
    float acc = ldw(tok_emb, (size_t)value[src] * NE + e, f32)
              + ldw(depth_emb, (size_t)depth[src] * NE + e, f32);
#pragma unroll
    for (int a = 0; a < NA; a++)
      acc += ldw(pos_emb, ((size_t)a * 65 + pos[src * NA + a]) * NE + e, f32);
    v = acc;
  }
  x[i] = v;
}

// ---------------- layer norm, one wave per row ----------------
__global__ __launch_bounds__(256) void ln_kernel(
    const float* __restrict__ x, const void* __restrict__ gam, const void* __restrict__ bet,
    size_t off, float* __restrict__ out, const int* __restrict__ dflag) {
  int f32 = dflag[0];
  int row = blockIdx.x * 4 + (threadIdx.x >> 6);
  int lane = threadIdx.x & 63;
  const float* xr = x + (size_t)row * NE;
  float v[8];
#pragma unroll
  for (int i = 0; i < 8; i++) v[i] = xr[lane + i * 64];
  float s = 0.f;
#pragma unroll
  for (int i = 0; i < 8; i++) s += v[i];
#pragma unroll
  for (int o = 32; o; o >>= 1) s += __shfl_xor(s, o);
  float m = s * (1.0f / NE);
  float sq = 0.f;
#pragma unroll
  for (int i = 0; i < 8; i++) { float d = v[i] - m; sq += d * d; }
#pragma unroll
  for (int o = 32; o; o >>= 1) sq += __shfl_xor(sq, o);
  float rs = 1.0f / sqrtf(sq * (1.0f / NE) + 1e-5f);
  float* orow = out + (size_t)row * NE;
#pragma unroll
  for (int i = 0; i < 8; i++) {
    int e = lane + i * 64;
    orow[e] = (v[i] - m) * rs * ldw(gam, off + e, f32) + ldw(bet, off + e, f32);
  }
}

// ---------------- GEMM core: 128x128 tile, BK=32, 8x8 microtile, packed f2v FMA ----------------
// Per-thread K accumulation is sequential k=0..K-1 (bit-stable across tilings).
template <int ACT>
__device__ __forceinline__ void gemm_body(
    const float* __restrict__ A, const void* __restrict__ Bw, size_t bwoff, int ldb,
    const void* bias, size_t biasoff, const float* resid, float* C,
    int N, int K, int f32, int bm, int bn) {
  __shared__ float As[32][132];   // [k][m]  16.9 KB
  __shared__ float Bs[32][132];   // [k][n]  16.9 KB
  int tid = threadIdx.x;
  int ty = tid >> 4, tx = tid & 15;
  f2v acc2[8][4];
#pragma unroll
  for (int i = 0; i < 8; i++)
#pragma unroll
    for (int j = 0; j < 4; j++) acc2[i][j] = (f2v){0.f, 0.f};
  int arow = tid >> 1;              // 0..127
  int acol = (tid & 1) << 4;        // 0 | 16
  int brow = tid >> 3;              // 0..31
  int bcol = (tid & 7) << 4;        // 0..112

  const float* Aptr = A + (size_t)(bm + arow) * K + acol;
  float4 pa[4];
  float4 pb[4];
  uint4 pbu[2];
#pragma unroll
  for (int j = 0; j < 4; j++) pa[j] = *(const float4*)(Aptr + 4 * j);
  {
    size_t boff = bwoff + (size_t)brow * ldb + bn + bcol;
    if (f32) {
#pragma unroll
      for (int j = 0; j < 4; j++) pb[j] = *(const float4*)((const float*)Bw + boff + 4 * j);
    } else {
      pbu[0] = *(const uint4*)((const bf16*)Bw + boff);
      pbu[1] = *(const uint4*)((const bf16*)Bw + boff + 8);
    }
  }

  for (int k0 = 0; k0 < K; k0 += 32) {
#pragma unroll
    for (int j = 0; j < 4; j++) {
      As[acol + 4 * j + 0][arow] = pa[j].x;
      As[acol + 4 * j + 1][arow] = pa[j].y;
      As[acol + 4 * j + 2][arow] = pa[j].z;
      As[acol + 4 * j + 3][arow] = pa[j].w;
    }
    if (f32) {
#pragma unroll
      for (int j = 0; j < 4; j++) {
        Bs[brow][bcol + 4 * j + 0] = pb[j].x;
        Bs[brow][bcol + 4 * j + 1] = pb[j].y;
        Bs[brow][bcol + 4 * j + 2] = pb[j].z;
        Bs[brow][bcol + 4 * j + 3] = pb[j].w;
      }
    } else {
      union { uint4 u; unsigned short s[8]; } r0, r1;
      r0.u = pbu[0]; r1.u = pbu[1];
#pragma unroll
      for (int j = 0; j < 8; j++) Bs[brow][bcol + j] = u2f(r0.s[j]);
#pragma unroll
      for (int j = 0; j < 8; j++) Bs[brow][bcol + 8 + j] = u2f(r1.s[j]);
    }
    __syncthreads();
    if (k0 + 32 < K) {
#pragma unroll
      for (int j = 0; j < 4; j++) pa[j] = *(const float4*)(Aptr + k0 + 32 + 4 * j);
      size_t boff = bwoff + (size_t)(k0 + 32 + brow) * ldb + bn + bcol;
      if (f32) {
#pragma unroll
        for (int j = 0; j < 4; j++) pb[j] = *(const float4*)((const float*)Bw + boff + 4 * j);
      } else {
        pbu[0] = *(const uint4*)((const bf16*)Bw + boff);
        pbu[1] = *(const uint4*)((const bf16*)Bw + boff + 8);
      }
    }
#pragma unroll
    for (int kk = 0; kk < 32; kk++) {
      float4 aA = *(const float4*)&As[kk][ty << 3];
      float4 aB = *(const float4*)&As[kk][(ty << 3) + 4];
      float4 bA = *(const float4*)&Bs[kk][tx << 2];          // cols tx*4..+3
      float4 bB = *(const float4*)&Bs[kk][64 + (tx << 2)];   // cols 64+tx*4..+3
      float av[8] = {aA.x, aA.y, aA.z, aA.w, aB.x, aB.y, aB.z, aB.w};
      f2v bv[4];
      bv[0] = (f2v){bA.x, bA.y};
      bv[1] = (f2v){bA.z, bA.w};
      bv[2] = (f2v){bB.x, bB.y};
      bv[3] = (f2v){bB.z, bB.w};
#pragma unroll
      for (int i = 0; i < 8; i++)
#pragma unroll
        for (int j = 0; j < 4; j++)
          acc2[i][j] += bv[j] * av[i];     // v_pk_fma_f32
    }
    __syncthreads();
  }
#pragma unroll
  for (int i = 0; i < 8; i++) {
    int row = bm + (ty << 3) + i;
    int c0 = bn + (tx << 2);
    int c1 = bn + 64 + (tx << 2);
    const float* ap = (const float*)&acc2[i][0];
    float o0[4], o1[4];
#pragma unroll
    for (int j = 0; j < 4; j++) { o0[j] = ap[j]; o1[j] = ap[4 + j]; }
    if (bias) {
#pragma unroll
      for (int j = 0; j < 4; j++) {
        o0[j] += ldw(bias, biasoff + c0 + j, f32);
        o1[j] += ldw(bias, biasoff + c1 + j, f32);
      }
    }
    if (ACT == 1) {
#pragma unroll
      for (int j = 0; j < 4; j++) {
        float t0 = 0.7978845608028654f * (o0[j] + 0.044715f * o0[j] * o0[j] * o0[j]);
        o0[j] = 0.5f * o0[j] * (1.0f + tanhf(t0));
        float t1 = 0.7978845608028654f * (o1[j] + 0.044715f * o1[j] * o1[j] * o1[j]);
        o1[j] = 0.5f * o1[j] * (1.0f + tanhf(t1));
      }
    }
    size_t p0 = (size_t)row * N + c0;
    size_t p1 = (size_t)row * N + c1;
    if (resid) {
      float4 r0 = *(const float4*)(resid + p0);
      float4 r1 = *(const float4*)(resid + p1);
      o0[0] += r0.x; o0[1] += r0.y; o0[2] += r0.z; o0[3] += r0.w;
      o1[0] += r1.x; o1[1] += r1.y; o1[2] += r1.z; o1[3] += r1.w;
    }
    *(float4*)(C + p0) = make_float4(o0[0], o0[1], o0[2], o0[3]);
    *(float4*)(C + p1) = make_float4(o1[0], o1[1], o1[2], o1[3]);
  }
}

template <int ACT>
__global__ __launch_bounds__(256) void gemm_kernel(
    const float* __restrict__ A, const void* __restrict__ Bw, size_t bwoff, int ldb,
    const void* bias, size_t biasoff, const float* resid, float* C,
    int N, int K, const int* __restrict__ dflag) {
  gemm_body<ACT>(A, Bw, bwoff, ldb, bias, biasoff, resid, C, N, K,
                 dflag[0], blockIdx.y << 7, blockIdx.x << 7);
}

// fused Q/K/V: blockIdx.x in [0,12): sel = x>>2 picks weight/output, (x&3) is column block
__global__ __launch_bounds__(256) void gemm_qkv_kernel(
    const float* __restrict__ A,
    const void* __restrict__ Wq, const void* __restrict__ Wk, const void* __restrict__ Wv,
    size_t bwoff, float* __restrict__ Cq, float* __restrict__ Ck, float* __restrict__ Cv,
    const int* __restrict__ dflag) {
  int sel = blockIdx.x >> 2;
  const void* Bw = (sel == 0) ? Wq : ((sel == 1) ? Wk : Wv);
  float* C = (sel == 0) ? Cq : ((sel == 1) ? Ck : Cv);
  gemm_body<0>(A, Bw, bwoff, NE, nullptr, 0, nullptr, C, NE, NE,
               dflag[0], blockIdx.y << 7, (blockIdx.x & 3) << 7);
}

// ---------------- normalized means in fp64 ----------------
__global__ __launch_bounds__(64) void mnd_kernel(const void* __restrict__ means,
                                                 double* __restrict__ mnd,
                                                 const int* __restrict__ dflag) {
  __shared__ double s[64];
  int f32 = dflag[0];
  int vblk = blockIdx.x;          // (l*NH + h)*NC + c
  int d = threadIdx.x;
  double m = (double)ldw(means, (size_t)vblk * ND + d, f32);
  s[d] = m * m;
  __syncthreads();
  for (int st = 32; st; st >>= 1) { if (d < st) s[d] += s[d + st]; __syncthreads(); }
  mnd[(size_t)vblk * ND + d] = m / (sqrt(s[0]) + 1e-8);
}

// ---------------- per-(token,head) 1/(||q||+1e-8) ----------------
__global__ __launch_bounds__(64) void rq_kernel(const float* __restrict__ q, double* __restrict__ rqd) {
  int bid = blockIdx.x;           // token*NH + head
  int tok = bid >> 3, h = bid & 7;
  int d = threadIdx.x;
  double v = (double)q[(size_t)tok * NE + h * ND + d];
  double ss = v * v;
#pragma unroll
  for (int o = 32; o; o >>= 1) ss += __shfl_xor(ss, o);
  if (d == 0) rqd[bid] = 1.0 / (sqrt(ss) + 1e-8);
}

// ---------------- routing: fp64 dists + exact top-64 via radix select ----------------
// blockIdx.x = c*32 + b*8 + h  (XCD swizzle: all blocks of head h share an XCD)
// keys unique (token index in low 12 bits) => exactly 64 keys >= 64th-largest.
// Output order is arbitrary: downstream (cnt/attn/scatter) is permutation-invariant.
__global__ __launch_bounds__(256) void route_kernel(
    const float* __restrict__ q, const double* __restrict__ mnd,
    const double* __restrict__ rqd, int* __restrict__ idxout) {
  __shared__ unsigned long long keys[NS];   // 32 KB
  __shared__ double mc[ND];
  __shared__ unsigned hist[256];
  __shared__ unsigned long long s_prefix;
  __shared__ unsigned s_rem, s_cnt;
  int bid = blockIdx.x;
  int h = bid & 7;
  int b = (bid >> 3) & 3;
  int c = bid >> 5;
  int bhc = ((b * NH + h) * NC) + c;
  int t = threadIdx.x;
  if (t < ND) mc[t] = mnd[((size_t)h * NC + c) * ND + t];
  if (t == 0) { s_prefix = 0ULL; s_rem = NW; s_cnt = 0u; }
  __syncthreads();
  for (int n = t; n < NS; n += 256) {
    const float4* qp = (const float4*)(q + (size_t)(b * NS + n) * NE + h * ND);
    double acc = 0.0;
#pragma unroll
    for (int j = 0; j < 16; j++) {
      float4 f = qp[j];
      acc += (double)f.x * mc[4 * j + 0];
      acc += (double)f.y * mc[4 * j + 1];
      acc += (double)f.z * mc[4 * j + 2];
      acc += (double)f.w * mc[4 * j + 3];
    }
    double dist = acc * rqd[(size_t)(b * NS + n) * NH + h];
    long long sb = __double_as_longlong(dist);
    unsigned long long u = (unsigned long long)sb;
    u = (sb < 0) ? ~u : (u | 0x8000000000000000ULL);
    keys[n] = (u & 0xFFFFFFFFFFFFF000ULL) | (unsigned long long)(NS - 1 - n);
  }
  __syncthreads();
  // 8 MSB-first passes of 8-bit radix select for the 64th-largest key
  for (int p = 7; p >= 0; p--) {
    int sh = p * 8;
    unsigned long long maskhi = (p == 7) ? 0ULL : (~0ULL << (sh + 8));
    hist[t] = 0u;
    __syncthreads();
    unsigned long long pref = s_prefix;
    for (int n = t; n < NS; n += 256) {
      unsigned long long k = keys[n];
      if ((k & maskhi) == pref) atomicAdd(&hist[(unsigned)((k >> sh) & 255ULL)], 1u);
    }
    __syncthreads();
    // inclusive suffix-sum: hist[t] = # matching keys with digit >= t
    for (int off = 1; off < 256; off <<= 1) {
      unsigned u = (t + off < 256) ? hist[t + off] : 0u;
      __syncthreads();
      hist[t] += u;
      __syncthreads();
    }
    unsigned rem = s_rem;
    if (hist[t] >= rem && (t == 255 || hist[t + 1] < rem)) {
      s_prefix = pref | ((unsigned long long)t << sh);
      s_rem = rem - ((t == 255) ? 0u : hist[t + 1]);
    }
    __syncthreads();
  }
  unsigned long long kth = s_prefix;   // exact 64th-largest key
  for (int n = t; n < NS; n += 256) {
    unsigned long long k = keys[n];
    if (k >= kth) {
      unsigned pos = atomicAdd(&s_cnt, 1u);
      idxout[(size_t)bhc * NW + pos] = (NS - 1) - (int)(k & 0xFFFULL);
    }
  }
}

// ---------------- per-(token,head) selection count ----------------
__global__ __launch_bounds__(256) void cnt_kernel(const int* __restrict__ idxb, float* __restrict__ cnt) {
  int i = blockIdx.x * 256 + threadIdx.x;   // NB*NH*NC*NW = 131072
  int bhc = i >> 6;
  int h = (bhc >> 6) & (NH - 1);
  int b = bhc >> 9;
  atomicAdd(&cnt[(size_t)(b * NS + idxb[i]) * NH + h], 1.0f);
}

// ---------------- bucket attention, all heads; scatter (attn/cnt) into obuf (pre-Wo) ----------------
__global__ __launch_bounds__(256) void attn_kernel(
    const float* __restrict__ q, const float* __restrict__ k, const float* __restrict__ v,
    const int* __restrict__ idxb, const int* __restrict__ value, const float* __restrict__ cnt,
    float* __restrict__ obuf) {
  __shared__ float qs[NW * (ND + 1)];
  __shared__ float ks[NW * (ND + 1)];
  __shared__ float sc[NW * (NW + 1)];
  __shared__ int idxs[NW];
  __shared__ float kmv[NW];
  __shared__ float cinv[NW];
  int bhc = blockIdx.x;                 // (b*NH + h)*NC + c
  int h = (bhc >> 6) & (NH - 1);
  int b = bhc >> 9;
  int t = threadIdx.x;
  if (t < NW) {
    int n = idxb[(size_t)bhc * NW + t];
    idxs[t] = n;
    kmv[t] = (value[b * NS + n] != 0) ? 1.f : 0.f;
    cinv[t] = 1.0f / fmaxf(cnt[(size_t)(b * NS + n) * NH + h], 1.0f);
  }
  __syncthreads();
  for (int p = t; p < NW * ND; p += 256) {
    int w = p >> 6, d = p & (ND - 1);
    size_t src = (size_t)(b * NS + idxs[w]) * NE + h * ND + d;
    qs[w * (ND + 1) + d] = q[src];
    ks[w * (ND + 1) + d] = k[src];
  }
  __syncthreads();
  for (int p = t; p < NW * NW; p += 256) {
    int w = p >> 6, x = p & (NW - 1);
    float dot = 0.f;
#pragma unroll 16
    for (int d = 0; d < ND; d++) dot += qs[w * (ND + 1) + d] * ks[x * (ND + 1) + d];
    bool allowed = (idxs[w] >= idxs[x]) && (kmv[x] != 0.f);
    sc[w * (NW + 1) + x] = allowed ? dot * 0.125f : -1e9f;
  }
  __syncthreads();
  if (t < NW) {
    float mx = -3.4e38f;
    for (int x = 0; x < NW; x++) mx = fmaxf(mx, sc[t * (NW + 1) + x]);
    float sum = 0.f;
    for (int x = 0; x < NW; x++) {
      float e = expf(sc[t * (NW + 1) + x] - mx);
      sc[t * (NW + 1) + x] = e;
      sum += e;
    }
    float inv = cinv[t] / sum;
    for (int x = 0; x < NW; x++) sc[t * (NW + 1) + x] *= inv;
  }
  for (int p = t; p < NW * ND; p += 256) {
    int w = p >> 6, d = p & (ND - 1);
    ks[w * (ND + 1) + d] = v[(size_t)(b * NS + idxs[w]) * NE + h * ND + d];
  }
  __syncthreads();
  for (int p = t; p < NW * ND; p += 256) {
    int w = p >> 6, d = p & (ND - 1);
    float o = 0.f;
#pragma unroll 16
    for (int x = 0; x < NW; x++) o += sc[w * (NW + 1) + x] * ks[x * (ND + 1) + d];
    qs[w * (ND + 1) + d] = o;
  }
  __syncthreads();
  for (int p = t; p < NW * ND; p += 256) {
    int w = p >> 6, d = p & (ND - 1);
    atomicAdd(&obuf[(size_t)(b * NS + idxs[w]) * NE + h * ND + d], qs[w * (ND + 1) + d]);
  }
}

// ---------------- head: out[b,s,v] = x . head_w[v]; dtype-aware output ----------------
__global__ __launch_bounds__(256) void head_kernel(
    const float* __restrict__ x, const void* __restrict__ hw, void* __restrict__ out,
    const int* __restrict__ dflag) {
  int f32 = dflag[0];
  int gw = (blockIdx.x * 256 + threadIdx.x) >> 6;
  int lane = threadIdx.x & 63;
  if (gw >= NTOK * NVOC) return;
  int row = gw / NVOC, vv = gw % NVOC;
  const float* xr = x + (size_t)row * NE;
  float acc = 0.f;
  for (int e = lane; e < NE; e += 64) acc += xr[e] * ldw(hw, (size_t)vv * NE + e, f32);
#pragma unroll
  for (int o = 32; o; o >>= 1) acc += __shfl_down(acc, o);
  if (lane == 0) {
    if (f32) ((float*)out)[(size_t)row * NVOC + vv] = acc;
    else ((bf16*)out)[(size_t)row * NVOC + vv] = __float2bfloat16(acc);
  }
}

extern "C" void kernel_launch(void* const* d_in, const int* in_sizes, int n_in,
                              void* d_out, int out_size, void* d_ws, size_t ws_size,
                              hipStream_t stream) {
  const int* value = (const int*)d_in[0];
  const int* depth = (const int*)d_in[1];
  const int* pos = (const int*)d_in[2];
  const void* sos = d_in[3];
  const void* tok_emb = d_in[4];
  const void* depth_emb = d_in[5];
  const void* pos_emb = d_in[6];
  const void* ln1_s = d_in[7];
  const void* ln1_b = d_in[8];
  const void* Wq = d_in[9];
  const void* Wk = d_in[10];
  const void* Wv = d_in[11];
  const void* Wo = d_in[12];
  const void* means = d_in[13];
  const void* ln2_s = d_in[14];
  const void* ln2_b = d_in[15];
  const void* W1 = d_in[16];
  const void* b1 = d_in[17];
  const void* W2 = d_in[18];
  const void* b2 = d_in[19];
  const void* head_w = d_in[20];
  (void)in_sizes; (void)n_in;

  const size_t NX = (size_t)NTOK * NE;                 // 8,388,608 floats (32 MiB)

  const size_t NEED = 170917896ULL;                    // ~163.0 MiB
  if (ws_size < NEED) {
    float val = (float)(unsigned)(ws_size >> 20) * 1000.0f;
    fill_out_kernel<<<(out_size + 255) / 256, 256, 0, stream>>>((float*)d_out, out_size, val);
    return;
  }

  float* xbuf = (float*)d_ws;
  float* hbuf = xbuf + NX;       // LN1 output, then pre-Wo attn accumulator
  float* qbuf = hbuf + NX;       // q all heads; later LN2 output
  float* kbuf = qbuf + NX;       // k; kbuf..vbuf doubles as FFN mid (64 MiB)
  float* vbuf = kbuf + NX;       // v
  double* mndbuf = (double*)(vbuf + NX);
  double* rqdbuf = mndbuf + (size_t)NL * NH * NC * ND;
  float* cntbuf = (float*)(rqdbuf + (size_t)NTOK * NH);
  int* idxbuf = (int*)(cntbuf + (size_t)NTOK * NH);
  int* dflag = idxbuf + (size_t)NB * NH * NC * NW;
  float* mid = kbuf;             // 8192 x 2048 fp32 = 64 MiB

  detect_kernel<<<1, 64, 0, stream>>>(tok_emb, dflag);
  mnd_kernel<<<NL * NH * NC, 64, 0, stream>>>(means, mndbuf, dflag);
  embed_kernel<<<(int)((NX + 255) / 256), 256, 0, stream>>>(
      value, depth, pos, sos, tok_emb, depth_emb, pos_emb, xbuf, dflag);

  const int CH = 8192;
  dim3 gqkv(12, NTOK / 128);                 // fused q,k,v: 1536 blocks
  dim3 g512(NE / 128, NTOK / 128);           // (4, 128)
  dim3 gW1(NF / 128, CH / 128);              // (16, 64)
  dim3 gW2(NE / 128, CH / 128);              // (4, 64)

  for (int l = 0; l < NL; l++) {
    size_t o_w = (size_t)l * NE * NE;
    size_t o_w1 = (size_t)l * NE * NF;
    size_t o_w2 = (size_t)l * NF * NE;
    size_t o_e = (size_t)l * NE;
    size_t o_f = (size_t)l * NF;

    ln_kernel<<<NTOK / 4, 256, 0, stream>>>(xbuf, ln1_s, ln1_b, o_e, hbuf, dflag);

    gemm_qkv_kernel<<<gqkv, 256, 0, stream>>>(hbuf, Wq, Wk, Wv, o_w, qbuf, kbuf, vbuf, dflag);

    rq_kernel<<<NTOK * NH, 64, 0, stream>>>(qbuf, rqdbuf);
    route_kernel<<<NB * NH * NC, 256, 0, stream>>>(
        qbuf, mndbuf + (size_t)l * NH * NC * ND, rqdbuf, idxbuf);
    zero_kernel<<<(NTOK * NH) / 256, 256, 0, stream>>>(cntbuf, NTOK * NH);
    cnt_kernel<<<(NB * NH * NC * NW) / 256, 256, 0, stream>>>(idxbuf, cntbuf);

    zero_kernel<<<(int)((NX + 255) / 256), 256, 0, stream>>>(hbuf, (int)NX);
    attn_kernel<<<NB * NH * NC, 256, 0, stream>>>(qbuf, kbuf, vbuf, idxbuf, value, cntbuf, hbuf);
    gemm_kernel<0><<<g512, 256, 0, stream>>>(hbuf, Wo, o_w, NE, nullptr, 0, xbuf,
                                             xbuf, NE, NE, dflag);

    ln_kernel<<<NTOK / 4, 256, 0, stream>>>(xbuf, ln2_s, ln2_b, o_e, qbuf, dflag);
    for (int ch = 0; ch < NTOK / CH; ch++) {
      const float* hch = qbuf + (size_t)ch * CH * NE;
      float* xch = xbuf + (size_t)ch * CH * NE;
      gemm_kernel<1><<<gW1, 256, 0, stream>>>(hch, W1, o_w1, NF, b1, o_f, nullptr,
                                              mid, NF, NE, dflag);
      gemm_kernel<0><<<gW2, 256, 0, stream>>>(mid, W2, o_w2, NE, b2, o_e, xch,
                                              xch, NE, NF, dflag);
    }
  }

  head_kernel<<<(NTOK * NVOC * 64 + 255) / 256, 256, 0, stream>>>(xbuf, head_w, d_out, dflag);
}